// Round 10
// baseline (89.948 us; speedup 1.0000x reference)
//
#include <hip/hip_runtime.h>

// Morph2D soft rank-order filter:
//   patches(3x3, zero-pad SAME) * se -> sort ascending -> dot softmax(rank)
// x: [32,512,512,1] fp32 -> out same shape.
//
// R10: cross-tile software pipelining. Each thread does TWO 4x4-px tiles
// (tile B = tile A + 16 images => same row offsets/halo/masks). All 24
// global loads issue before any compute; B's loads stay in flight under
// A's compute. Ternary min3/med3/max3 sort, shuffle halo, plain
// __launch_bounds__(256) (occupancy-arg variants spill: R5/R7 evidence).

#define HH 512
#define WW 512

#define RFL(x) __int_as_float(__builtin_amdgcn_readfirstlane(__float_as_int(x)))
#define MIN3(a,b,c) fminf(fminf(a,b),c)
#define MAX3(a,b,c) fmaxf(fmaxf(a,b),c)
#define MED3(a,b,c) __builtin_amdgcn_fmed3f(a,b,c)
#define TSORT(a,b,c) { float t0_=MIN3(a,b,c), t1_=MED3(a,b,c), t2_=MAX3(a,b,c); a=t0_; b=t1_; c=t2_; }

// weight/sort/dot + store for one 4x4 tile from loaded regs CC[6]/EG[6]
#define COMPUTE_TILE(CC, EG, OUTP)                                           \
    {                                                                        \
        float R[6][6];                                                       \
        _Pragma("unroll")                                                    \
        for (int r = 0; r < 6; ++r) {                                        \
            float lw = __shfl_up(CC[r].w, 1);                                \
            float rx = __shfl_down(CC[r].x, 1);                              \
            float lf = (lane == 0)  ? EG[r] : lw;                            \
            float rt = (lane == 63) ? EG[r] : rx;                            \
            float m  = mrow[r];                                              \
            R[r][0] = lf * m;      R[r][1] = CC[r].x * m;                    \
            R[r][2] = CC[r].y * m; R[r][3] = CC[r].z * m;                    \
            R[r][4] = CC[r].w * m; R[r][5] = rt * m;                         \
        }                                                                    \
        _Pragma("unroll")                                                    \
        for (int r = 0; r < 4; ++r) {                                        \
            float res[4];                                                    \
            _Pragma("unroll")                                                \
            for (int j = 0; j < 4; ++j) {                                    \
                float v0 = R[r  ][j]*s0, v1 = R[r  ][j+1]*s1, v2 = R[r  ][j+2]*s2; \
                float v3 = R[r+1][j]*s3, v4 = R[r+1][j+1]*s4, v5 = R[r+1][j+2]*s5; \
                float v6 = R[r+2][j]*s6, v7 = R[r+2][j+1]*s7, v8 = R[r+2][j+2]*s8; \
                TSORT(v0, v1, v2) TSORT(v3, v4, v5) TSORT(v6, v7, v8)        \
                TSORT(v0, v3, v6) TSORT(v1, v4, v7) TSORT(v2, v5, v8)        \
                float r1 = fminf(v1, v3), p = fmaxf(v1, v3);                 \
                float r7 = fmaxf(v5, v7), q = fminf(v5, v7);                 \
                TSORT(v2, v4, v6)                                            \
                float r2 = fminf(p, v2), r3 = fmaxf(p, v2);                  \
                float r5 = fminf(q, v6), r6 = fmaxf(q, v6);                  \
                float acc = v0 * w0;                                         \
                acc = fmaf(r1, w1, acc); acc = fmaf(r2, w2, acc);            \
                acc = fmaf(r3, w3, acc); acc = fmaf(v4, w4, acc);            \
                acc = fmaf(r5, w5, acc); acc = fmaf(r6, w6, acc);            \
                acc = fmaf(r7, w7, acc); acc = fmaf(v8, w8, acc);            \
                res[j] = acc;                                                \
            }                                                                \
            float4 o = { res[0], res[1], res[2], res[3] };                   \
            *(float4*)((OUTP) + (size_t)r * WW) = o;                         \
        }                                                                    \
    }

__global__ __launch_bounds__(256) void morph2d_kernel(
    const float* __restrict__ x, const float* __restrict__ se9,
    const float* __restrict__ rank, float* __restrict__ out)
{
    // XCD-aware swizzle: contiguous chunk of blocks per XCD
    int nper = gridDim.x >> 3;
    int lb   = (blockIdx.x & 7) * nper + (blockIdx.x >> 3);
    int g    = lb * 256 + threadIdx.x;       // 262,144 threads

    int gx = g & 127;             // x-group of 4 px
    int rg = (g >> 7) & 127;      // row-group of 4 rows (wave-uniform)
    int b0 = g >> 14;             // batch A in [0,16); batch B = b0+16
    int x4 = gx << 2;
    int y0 = rg << 2;
    int lane = threadIdx.x & 63;

    const float* imgA = x + (size_t)b0 * (HH * WW);
    const float* imgB = imgA + (size_t)16 * (HH * WW);

    // wave-edge halo lanes: lane 0 loads col x4-1, lane 63 loads col x4+4
    bool eL = (lane == 0)  && (x4 > 0);
    bool eR = (lane == 63) && (x4 + 4 < WW);
    bool eAny = eL || eR;
    int  eoff = eL ? (x4 - 1) : (x4 + 4);

    // row offsets + y-border masks (identical for both tiles)
    int   rowoff[6];
    float mrow[6];
    #pragma unroll
    for (int r = 0; r < 6; ++r) {
        int ry = y0 - 1 + r;
        rowoff[r] = min(max(ry, 0), HH - 1) * WW;
        mrow[r]   = (ry >= 0 && ry < HH) ? 1.f : 0.f;
    }

    // ---- issue ALL loads: tile A then tile B (B stays in flight) ----
    float4 cA[6]; float egA[6];
    #pragma unroll
    for (int r = 0; r < 6; ++r) {
        const float* p = imgA + rowoff[r];
        cA[r]  = *(const float4*)(p + x4);
        egA[r] = eAny ? p[eoff] : 0.f;
    }
    float4 cB[6]; float egB[6];
    #pragma unroll
    for (int r = 0; r < 6; ++r) {
        const float* p = imgB + rowoff[r];
        cB[r]  = *(const float4*)(p + x4);
        egB[r] = eAny ? p[eoff] : 0.f;
    }

    // ---- softmax(rank) (1/s folded) + se, scalarized, under load shadow ----
    float w0,w1,w2,w3,w4,w5,w6,w7,w8;
    float s0,s1,s2,s3,s4,s5,s6,s7,s8;
    {
        float e[9]; float s = 0.f;
        #pragma unroll
        for (int i = 0; i < 9; ++i) { e[i] = __expf(rank[i]); s += e[i]; }
        float inv = 1.0f / s;
        w0=RFL(e[0]*inv); w1=RFL(e[1]*inv); w2=RFL(e[2]*inv);
        w3=RFL(e[3]*inv); w4=RFL(e[4]*inv); w5=RFL(e[5]*inv);
        w6=RFL(e[6]*inv); w7=RFL(e[7]*inv); w8=RFL(e[8]*inv);
        s0=RFL(se9[0]); s1=RFL(se9[1]); s2=RFL(se9[2]); s3=RFL(se9[3]);
        s4=RFL(se9[4]); s5=RFL(se9[5]); s6=RFL(se9[6]); s7=RFL(se9[7]); s8=RFL(se9[8]);
    }

    // ---- compute/store tile A (B's loads still in flight), then B ----
    float* outA = out + ((size_t)b0 * HH + y0) * WW + x4;
    COMPUTE_TILE(cA, egA, outA)
    float* outB = outA + (size_t)16 * (HH * WW);
    COMPUTE_TILE(cB, egB, outB)
}

extern "C" void kernel_launch(void* const* d_in, const int* in_sizes, int n_in,
                              void* d_out, int out_size, void* d_ws, size_t ws_size,
                              hipStream_t stream) {
    const float* x    = (const float*)d_in[0];
    const float* se   = (const float*)d_in[1];
    const float* rank = (const float*)d_in[2];
    float* out = (float*)d_out;

    const int total_threads = 32 * (HH / 4) * (WW / 4) / 2;   // 262,144
    morph2d_kernel<<<total_threads / 256, 256, 0, stream>>>(x, se, rank, out);
}